// Round 6
// baseline (33.696 us; speedup 1.0000x reference)
//
#include <hip/hip_runtime.h>
#include <math.h>

// Problem constants (fixed by setup_inputs)
#define B_   8
#define S_   512
#define MV_  8        // M_VALID
#define D_   512
#define R_   16
#define MOUT (R_ + 1)            // 17 output slots per (b,s)

typedef float f32x4 __attribute__((ext_vector_type(4)));

// One block per (b,s). 256 threads: threads 0-127 (waves 0,1) do even m
// (9 rows), threads 128-255 (waves 2,3) odd m (8 rows). Each thread owns a
// fixed d-position d4=(t&127)*4 -> its PE values are loop-invariant
// registers. No LDS, no barriers. The m-loop is fully unrolled with source
// pointers resolved up front so the compiler can issue all gather loads
// before the add/store chain (max memory-level parallelism).
__global__ __launch_bounds__(256) void block_revert_fused(
    const float* __restrict__ temporal,   // [B][S][MV+1][D]
    const float* __restrict__ mask_token, // [D]
    const float* __restrict__ mod_emb,    // [R+1][D]
    const int*   __restrict__ revert_idx, // [B][S][R]
    float*       __restrict__ out)        // [B][S][MOUT][D]
{
    const int bs   = blockIdx.x;          // b*S + s
    const int s    = bs & (S_ - 1);
    const int t    = threadIdx.x;
    const int half = t >> 7;              // 0/1 (wave-uniform)
    const int d4   = (t & 127) * 4;       // fixed float offset within a row

    // Per-thread loop-invariant PE values: pairs j0 = d4/2, j0+1.
    const float kNegLn10kOverD = -9.210340371976184f / (float)D_;
    const int j0 = d4 >> 1;
    float f0 = expf((float)(2 * j0)       * kNegLn10kOverD);
    float f1 = expf((float)(2 * (j0 + 1)) * kNegLn10kOverD);
    float s0, c0, s1, c1;
    sincosf((float)s * f0, &s0, &c0);
    sincosf((float)s * f1, &s1, &c1);
    f32x4 p;
    p.x = s0; p.y = c0; p.z = s1; p.w = c1;

    const float* __restrict__ base = temporal + (size_t)bs * ((MV_ + 1) * D_);
    const int*   __restrict__ idxp = revert_idx + bs * R_;
    float*       __restrict__ outb = out + (size_t)bs * (MOUT * D_);

    // 9 rows for half==0 (m = 0,2,...,16), 8 rows for half==1 (m = 1,3,...,15)
    const int nrows = 9 - half;

    const float* srcs[9];
    f32x4        vals[9];

    // Resolve all source pointers (wave-uniform; idx loads are s-buffer
    // broadcasts through L1).
    #pragma unroll
    for (int i = 0; i < 9; ++i) {
        if (i < nrows) {
            int m = 2 * i + half;
            if (m == 0) {
                srcs[i] = base;
            } else {
                int idx = idxp[m - 1];
                srcs[i] = (idx < MV_) ? (base + (size_t)(1 + idx) * D_)
                                      : mask_token;
            }
        }
    }

    // Issue all gather loads first (MLP), then add + nontemporal store.
    #pragma unroll
    for (int i = 0; i < 9; ++i) {
        if (i < nrows)
            vals[i] = *reinterpret_cast<const f32x4*>(srcs[i] + d4);
    }

    #pragma unroll
    for (int i = 0; i < 9; ++i) {
        if (i < nrows) {
            int m = 2 * i + half;
            f32x4 me = *reinterpret_cast<const f32x4*>(mod_emb + m * D_ + d4);
            f32x4 o  = vals[i] + p + me;
            __builtin_nontemporal_store(o,
                reinterpret_cast<f32x4*>(outb + (size_t)m * D_ + d4));
        }
    }
}

extern "C" void kernel_launch(void* const* d_in, const int* in_sizes, int n_in,
                              void* d_out, int out_size, void* d_ws, size_t ws_size,
                              hipStream_t stream) {
    const float* temporal   = (const float*)d_in[0];
    const float* mask_token = (const float*)d_in[1];
    const float* mod_emb    = (const float*)d_in[2];
    const int*   revert_idx = (const int*)d_in[3];
    float*       out        = (float*)d_out;

    block_revert_fused<<<B_ * S_, 256, 0, stream>>>(
        temporal, mask_token, mod_emb, revert_idx, out);
}

// Round 7
// 32.573 us; speedup vs baseline: 1.0345x; 1.0345x over previous
//
#include <hip/hip_runtime.h>
#include <math.h>

// Problem constants (fixed by setup_inputs)
#define B_   8
#define S_   512
#define MV_  8        // M_VALID
#define D_   512
#define R_   16
#define MOUT (R_ + 1)            // 17 output slots per (b,s)
#define F4_PER_ROW (D_ / 4)      // 128
#define F4_PER_BS  (MOUT * F4_PER_ROW) // 2176

typedef float f32x4 __attribute__((ext_vector_type(4)));

// Best measured variant (R3, 32.7 us): one block per (b,s), PE row staged
// once in LDS, 16 gather indices in LDS, 17 rows streamed as float4 with
// nontemporal stores. All gather branches wave-uniform.
__global__ __launch_bounds__(256) void block_revert_fused(
    const float* __restrict__ temporal,   // [B][S][MV+1][D]
    const float* __restrict__ mask_token, // [D]
    const float* __restrict__ mod_emb,    // [R+1][D]
    const int*   __restrict__ revert_idx, // [B][S][R]
    float*       __restrict__ out)        // [B][S][MOUT][D]
{
    __shared__ float s_pe[D_];
    __shared__ int   s_idx[R_];

    const int bs = blockIdx.x;            // b*S + s
    const int s  = bs & (S_ - 1);
    const int t  = threadIdx.x;

    // PE row for this s: thread t computes pair j = t (D/2 = 256 pairs).
    {
        const float kNegLn10kOverD = -9.210340371976184f / (float)D_;
        float freq = expf((float)(2 * t) * kNegLn10kOverD);
        float sn, cs;
        sincosf((float)s * freq, &sn, &cs);
        s_pe[2 * t]     = sn;
        s_pe[2 * t + 1] = cs;
    }
    if (t < R_) s_idx[t] = revert_idx[bs * R_ + t];
    __syncthreads();

    const float* base = temporal + (size_t)bs * (MV_ + 1) * D_;
    float*       outb = out + (size_t)bs * MOUT * D_;

    for (int f4 = t; f4 < F4_PER_BS; f4 += 256) {
        int m  = f4 >> 7;          // output row 0..16 (wave-uniform)
        int d4 = (f4 & 127) * 4;   // float offset within row

        const float* src;
        if (m == 0) {
            src = base;                                   // global slot
        } else {
            int idx = s_idx[m - 1];
            src = (idx < MV_) ? (base + (size_t)(1 + idx) * D_)
                              : mask_token;               // mask fill
        }

        f32x4 v  = *reinterpret_cast<const f32x4*>(src + d4);
        f32x4 p  = *reinterpret_cast<const f32x4*>(s_pe + d4);
        f32x4 me = *reinterpret_cast<const f32x4*>(mod_emb + m * D_ + d4);

        f32x4 o = v + p + me;

        __builtin_nontemporal_store(o,
            reinterpret_cast<f32x4*>(outb + (size_t)m * D_ + d4));
    }
}

extern "C" void kernel_launch(void* const* d_in, const int* in_sizes, int n_in,
                              void* d_out, int out_size, void* d_ws, size_t ws_size,
                              hipStream_t stream) {
    const float* temporal   = (const float*)d_in[0];
    const float* mask_token = (const float*)d_in[1];
    const float* mod_emb    = (const float*)d_in[2];
    const int*   revert_idx = (const int*)d_in[3];
    float*       out        = (float*)d_out;

    block_revert_fused<<<B_ * S_, 256, 0, stream>>>(
        temporal, mask_token, mod_emb, revert_idx, out);
}